// Round 13
// baseline (172.274 us; speedup 1.0000x reference)
//
#include <hip/hip_runtime.h>
#include <hip/hip_bf16.h>

typedef __bf16 bf16x8 __attribute__((ext_vector_type(8)));
typedef __bf16 bf16x4 __attribute__((ext_vector_type(4)));
typedef float  f32x4  __attribute__((ext_vector_type(4)));

#define DM 1024
#define PD 3328
#define TROWS 8192   // bs*seq = 2*4096
#define SEQ 4096

__device__ __forceinline__ float sigmoidf(float x) { return 1.f / (1.f + __expf(-x)); }

__device__ __forceinline__ void gload16(const void* g, void* l) {
  __builtin_amdgcn_global_load_lds(
      (const __attribute__((address_space(1))) void*)g,
      (__attribute__((address_space(3))) void*)l, 16, 0, 0);
}

// ---------------- fused prep: tcvt(Win) + tcvt(Wout) + rmsnorm in ONE launch
__global__ __launch_bounds__(256) void prep_kernel(const float* __restrict__ Win,
                                                   __bf16* __restrict__ WinT,
                                                   const float* __restrict__ Wout,
                                                   __bf16* __restrict__ WoutT,
                                                   const float* __restrict__ hidden,
                                                   const float* __restrict__ rmsw,
                                                   __bf16* __restrict__ hbf) {
  const int id = blockIdx.x;
  const int tid = threadIdx.x;
  if (id < 4352) {
    __shared__ float tile[32][33];
    const float* in;  __bf16* out;  int K, N, bx, by;
    if (id < 3328) { in = Win;  out = WinT;  K = DM; N = PD; bx = id % 104; by = id / 104; }
    else           { in = Wout; out = WoutT; K = DM; N = DM; bx = (id - 3328) & 31; by = (id - 3328) >> 5; }
    int n0 = bx * 32, k0 = by * 32;
    int tx = tid & 31, ty = tid >> 5;   // 32 x 8
    for (int i = ty; i < 32; i += 8) tile[i][tx] = in[(size_t)(k0 + i) * N + n0 + tx];
    __syncthreads();
    for (int i = ty; i < 32; i += 8) out[(size_t)(n0 + i) * K + k0 + tx] = (__bf16)tile[tx][i];
  } else {
    int r = id - 4352;
    float4 v = ((const float4*)(hidden + (size_t)r * DM))[tid];
    float ss = v.x * v.x + v.y * v.y + v.z * v.z + v.w * v.w;
#pragma unroll
    for (int off = 32; off > 0; off >>= 1) ss += __shfl_xor(ss, off);
    __shared__ float wsum[4];
    int lane = tid & 63, wid = tid >> 6;
    if (lane == 0) wsum[wid] = ss;
    __syncthreads();
    float tot = wsum[0] + wsum[1] + wsum[2] + wsum[3];
    float inv = rsqrtf(tot * (1.f / 1024.f) + 1e-6f);
    float4 wl = ((const float4*)rmsw)[tid];
    bf16x4 o;
    o[0] = (__bf16)(v.x * inv * wl.x);
    o[1] = (__bf16)(v.y * inv * wl.y);
    o[2] = (__bf16)(v.z * inv * wl.z);
    o[3] = (__bf16)(v.w * inv * wl.w);
    *(bf16x4*)(hbf + (size_t)r * DM + tid * 4) = o;
  }
}

// ---------------- 2-phase MFMA GEMM 128x128/BK=64 (R6/R10-verified 91.8 us)
// with GM x GN grouped XCD mapping (R12-verified: GM=4 cuts FETCH to ~43 MB).
template <int GM, int GN, int EPI>
__global__ __launch_bounds__(512, 4) void gemm2p(
    const __bf16* __restrict__ A, const __bf16* __restrict__ Bt,
    int N_out, int K,
    const float* __restrict__ gate_bias, const float* __restrict__ shortcut,
    float* __restrict__ outf, __bf16* __restrict__ zbf, __bf16* __restrict__ xbf,
    __bf16* __restrict__ gbf, __bf16* __restrict__ qbf, __bf16* __restrict__ kbf) {
  __shared__ __bf16 As[2][128 * 64];
  __shared__ __bf16 Bs[2][128 * 64];

  const int tid = threadIdx.x;
  const int lane = tid & 63, wid = tid >> 6;   // wid 0..7
  const int wr = wid >> 1, wc = wid & 1;       // 4 x 2 waves, wave tile 32(m) x 64(n)

  // XCD-aware bijective swizzle (grid sizes are multiples of 8)
  const int nwg = gridDim.x;
  const int cpx = nwg >> 3;
  const int swz = (blockIdx.x & 7) * cpx + (blockIdx.x >> 3);
  // grouped 2D mapping: group = GM(m) x GN(n) tiles (L2 working set ~4.4 MB)
  const int ntx = N_out >> 7;
  const int ngn = ntx / GN;
  const int g = swz / (GM * GN), l = swz % (GM * GN);
  const int gm = g / ngn, gn = g % ngn;
  const int m0 = (gm * GM + (l % GM)) << 7;
  const int n0 = (gn * GN + (l / GM)) << 7;

  f32x4 acc[2][4] = {};
  const int NT = K >> 6;

  const int arow0 = wr * 32 + (lane & 15);
  const int brow0 = wc * 64 + (lane & 15);

  auto stage = [&](const __bf16* src, int row0, int kt, __bf16* lbuf) {
#pragma unroll
    for (int j = 0; j < 2; ++j) {
      int off16 = tid + j * 512;        // 16B-chunk index; 8 chunks per row
      int row = off16 >> 3, slot = off16 & 7;
      int col = (slot ^ (row & 7)) << 3;  // inverse swizzle on the SOURCE
      gload16(&src[(size_t)(row0 + row) * K + kt + col], lbuf + off16 * 8);
    }
  };
  auto fragrd = [&](const __bf16* buf, int row, int ks) -> bf16x8 {
    int s = ((ks << 2) + (lane >> 4)) ^ (row & 7);   // swizzled read
    return *(const bf16x8*)&buf[(row << 6) + (s << 3)];
  };

  // prologue: tile 0
  stage(A, m0, 0, &As[0][0]);
  stage(Bt, n0, 0, &Bs[0][0]);
  asm volatile("s_waitcnt vmcnt(0)" ::: "memory");
  __builtin_amdgcn_s_barrier();

  for (int t = 0; t < NT; ++t) {
    const __bf16* Ap = &As[t & 1][0];
    const __bf16* Bp = &Bs[t & 1][0];
    if (t + 1 < NT) {
      stage(A, m0, (t + 1) << 6, &As[(t + 1) & 1][0]);
      stage(Bt, n0, (t + 1) << 6, &Bs[(t + 1) & 1][0]);
    }
#pragma unroll
    for (int ks = 0; ks < 2; ++ks) {
      bf16x8 af[2], bf[4];
#pragma unroll
      for (int m = 0; m < 2; ++m) af[m] = fragrd(Ap, arow0 + m * 16, ks);
#pragma unroll
      for (int n = 0; n < 4; ++n) bf[n] = fragrd(Bp, brow0 + n * 16, ks);
      __builtin_amdgcn_s_setprio(1);
#pragma unroll
      for (int m = 0; m < 2; ++m)
#pragma unroll
        for (int n = 0; n < 4; ++n)
          acc[m][n] = __builtin_amdgcn_mfma_f32_16x16x32_bf16(af[m], bf[n], acc[m][n], 0, 0, 0);
      __builtin_amdgcn_s_setprio(0);
    }
    asm volatile("s_waitcnt vmcnt(0)" ::: "memory");
    __builtin_amdgcn_s_barrier();
  }

  // epilogue: C/D map col=lane&15, row=(lane>>4)*4+i
#pragma unroll
  for (int m = 0; m < 2; ++m) {
#pragma unroll
    for (int n = 0; n < 4; ++n) {
#pragma unroll
      for (int i = 0; i < 4; ++i) {
        int r = m0 + wr * 32 + m * 16 + ((lane >> 4) << 2) + i;
        int c = n0 + wc * 64 + n * 16 + (lane & 15);
        float v = acc[m][n][i];
        if (EPI == 1) {
          if (c < 1024)       zbf[(size_t)r * DM + c] = (__bf16)sigmoidf(v);
          else if (c < 2048)  xbf[(size_t)r * DM + (c - 1024)] = (__bf16)v;
          else if (c < 3072)  gbf[(size_t)r * DM + (c - 2048)] = (__bf16)sigmoidf(v + gate_bias[c - 2048]);
          else if (c < 3200)  qbf[(size_t)r * 128 + (c - 3072)] = (__bf16)v;
          else                kbf[(size_t)r * 128 + (c - 3200)] = (__bf16)v;
        } else {
          outf[(size_t)r * DM + c] = v + shortcut[(size_t)r * DM + c];
        }
      }
    }
  }
}

// ---------------- per-chunk first-order scan; also emits chunk_x TRANSPOSED
__global__ __launch_bounds__(256) void scan_kernel(const __bf16* __restrict__ g,
                                                   const __bf16* __restrict__ x,
                                                   const __bf16* __restrict__ kin,
                                                   __bf16* __restrict__ ixa,
                                                   __bf16* __restrict__ ika,
                                                   __bf16* __restrict__ cxtg) {
  int bx = blockIdx.x;            // 2*64*4 = 512 blocks
  int part = bx & 3;
  int c = (bx >> 2) & 63;
  int b = bx >> 8;
  int d = part * 256 + threadIdx.x;
  size_t base = (size_t)b * SEQ + (size_t)c * 64;
  float sx = 0.f, sk = 0.f;
  for (int t = 0; t < 64; ++t) {
    size_t row = base + t;
    float gg = (float)g[row * DM + d];
    float xv = (float)x[row * DM + d];
    float kv = (float)kin[row * 128 + (d & 127)];
    sx = gg * (sx - xv) + xv;   // = g*prev + (1-g)*x
    sk = gg * (sk - kv) + kv;
    ixa[row * DM + d] = (__bf16)sx;
    ika[row * DM + d] = (__bf16)sk;
    if (t == 0) cxtg[((size_t)b * DM + d) * 64 + c] = (__bf16)sx;
  }
}

// ---------------- attention v2 (R10-measured): block = (qtile, head, batch)
__global__ __launch_bounds__(256) void attn_kernel(const __bf16* __restrict__ qbf,
                                                   const __bf16* __restrict__ ixa,
                                                   const __bf16* __restrict__ ika,
                                                   const __bf16* __restrict__ cxtg,
                                                   const __bf16* __restrict__ zbf,
                                                   __bf16* __restrict__ y) {
  const int qt = blockIdx.x;   // 0..63 query chunk
  const int h  = blockIdx.y;   // 0..15
  const int b  = blockIdx.z;   // 0..1
  const int tid = threadIdx.x;
  const int lane = tid & 63, wd = tid >> 6;

  __shared__ __bf16 qs[64 * 72];    // q rows [s][d]
  __shared__ __bf16 ck[64 * 72];    // chunk_k rows [c][d]
  __shared__ __bf16 cxT[64 * 72];   // chunk_x transposed [j][c]
  __shared__ __bf16 pb[64 * 72];    // softmax weights [s][c]
  __shared__ float sc[64 * 65];     // scores [s][c]
  __shared__ float rden[64], iwd[64], rlse[64];

  const size_t base = (size_t)b * SEQ;

  for (int i = tid; i < 512; i += 256) {
    int row = i >> 3, part = i & 7;
    *(bf16x8*)&qs[row * 72 + part * 8] =
        *(const bf16x8*)&qbf[(base + qt * 64 + row) * 128 + (h & 1) * 64 + part * 8];
    *(bf16x8*)&ck[row * 72 + part * 8] =
        *(const bf16x8*)&ika[(base + (size_t)row * 64) * DM + h * 64 + part * 8];
    *(bf16x8*)&cxT[row * 72 + part * 8] =
        *(const bf16x8*)&cxtg[((size_t)b * DM + h * 64 + row) * 64 + part * 8];
  }
  __syncthreads();

  // scores = scale * Q . chunk_k^T  -> sc[s][c]
  {
    f32x4 d4[4] = {};
#pragma unroll
    for (int kk = 0; kk < 64; kk += 32) {
      bf16x8 a = *(const bf16x8*)&qs[(wd * 16 + (lane & 15)) * 72 + kk + (lane >> 4) * 8];
#pragma unroll
      for (int ni = 0; ni < 4; ++ni) {
        bf16x8 bb = *(const bf16x8*)&ck[(ni * 16 + (lane & 15)) * 72 + kk + (lane >> 4) * 8];
        d4[ni] = __builtin_amdgcn_mfma_f32_16x16x32_bf16(a, bb, d4[ni], 0, 0, 0);
      }
    }
#pragma unroll
    for (int ni = 0; ni < 4; ++ni)
#pragma unroll
      for (int i = 0; i < 4; ++i) {
        int qrow = wd * 16 + (lane >> 4) * 4 + i;
        int c = ni * 16 + (lane & 15);
        sc[qrow * 65 + c] = 0.125f * d4[ni][i];
      }
  }

  // intra_lse, 4 lanes per q-row
  {
    int s = tid >> 2, p = tid & 3;
    const __bf16* krow = &ika[(base + qt * 64 + s) * DM + h * 64 + p * 16];
    float dot = 0.f;
#pragma unroll
    for (int half = 0; half < 2; ++half) {
      bf16x8 qa = *(const bf16x8*)&qs[s * 72 + p * 16 + half * 8];
      bf16x8 ka = *(const bf16x8*)&krow[half * 8];
#pragma unroll
      for (int e = 0; e < 8; ++e) dot += (float)qa[e] * (float)ka[e];
    }
    dot += __shfl_xor(dot, 1);
    dot += __shfl_xor(dot, 2);
    if (p == 0) rlse[s] = 0.125f * dot;
  }
  __syncthreads();

  // softmax, 4 lanes per q-row
  {
    int s = tid >> 2, p = tid & 3;
    float lse = rlse[s];
    float m = -1e30f;
#pragma unroll
    for (int k = 0; k < 16; ++k) {
      int c = p * 16 + k;
      if (c < qt) m = fmaxf(m, sc[s * 65 + c]);
    }
    m = fmaxf(m, __shfl_xor(m, 1));
    m = fmaxf(m, __shfl_xor(m, 2));
    m = fmaxf(m, lse);
    float den = 0.f;
    bf16x8 w0, w1;
#pragma unroll
    for (int k = 0; k < 16; ++k) {
      int c = p * 16 + k;
      float wv = (c < qt) ? __expf(sc[s * 65 + c] - m) : 0.f;
      if (k < 8) w0[k] = (__bf16)wv; else w1[k - 8] = (__bf16)wv;
      den += wv;
    }
    *(bf16x8*)&pb[s * 72 + p * 16] = w0;
    *(bf16x8*)&pb[s * 72 + p * 16 + 8] = w1;
    den += __shfl_xor(den, 1);
    den += __shfl_xor(den, 2);
    float iw = __expf(lse - m);
    if (p == 0) {
      rden[s] = 1.f / (den + iw);
      iwd[s] = iw;
    }
  }
  __syncthreads();

  // PV: out[s][j] = sum_c pb[s][c] * cxT[j][c]
  {
    f32x4 d4[4] = {};
#pragma unroll
    for (int kk = 0; kk < 64; kk += 32) {
      bf16x8 a = *(const bf16x8*)&pb[(wd * 16 + (lane & 15)) * 72 + kk + (lane >> 4) * 8];
#pragma unroll
      for (int ni = 0; ni < 4; ++ni) {
        bf16x8 bb = *(const bf16x8*)&cxT[(ni * 16 + (lane & 15)) * 72 + kk + (lane >> 4) * 8];
        d4[ni] = __builtin_amdgcn_mfma_f32_16x16x32_bf16(a, bb, d4[ni], 0, 0, 0);
      }
    }
#pragma unroll
    for (int ni = 0; ni < 4; ++ni)
#pragma unroll
      for (int i = 0; i < 4; ++i) {
        int qrow = wd * 16 + (lane >> 4) * 4 + i;
        int j = ni * 16 + (lane & 15);
        size_t srow = base + qt * 64 + qrow;
        float ix = (float)ixa[srow * DM + h * 64 + j];
        float outv = (d4[ni][i] + iwd[qrow] * ix) * rden[qrow];
        float zv = (float)zbf[srow * DM + h * 64 + j];
        y[srow * DM + h * 64 + j] = (__bf16)(outv * zv);
      }
  }
}

// ---------------- launcher
extern "C" void kernel_launch(void* const* d_in, const int* in_sizes, int n_in,
                              void* d_out, int out_size, void* d_ws, size_t ws_size,
                              hipStream_t stream) {
  const float* hidden = (const float*)d_in[0];
  const float* rmsw   = (const float*)d_in[1];
  const float* Win    = (const float*)d_in[2];
  const float* gbias  = (const float*)d_in[3];
  const float* Wout   = (const float*)d_in[4];
  float* out = (float*)d_out;

  char* ws = (char*)d_ws;
  size_t o = 0;
  auto alloc = [&](size_t bytes) { char* p = ws + o; o += (bytes + 255) & ~(size_t)255; return p; };
  __bf16* WinT  = (__bf16*)alloc((size_t)PD * DM * 2);
  __bf16* WoutT = (__bf16*)alloc((size_t)DM * DM * 2);
  __bf16* hy    = (__bf16*)alloc((size_t)TROWS * DM * 2);  // h_bf, reused as y after GEMM1
  __bf16* zbf   = (__bf16*)alloc((size_t)TROWS * DM * 2);
  __bf16* xbf   = (__bf16*)alloc((size_t)TROWS * DM * 2);
  __bf16* gbf   = (__bf16*)alloc((size_t)TROWS * DM * 2);
  __bf16* qbf   = (__bf16*)alloc((size_t)TROWS * 128 * 2);
  __bf16* kbf   = (__bf16*)alloc((size_t)TROWS * 128 * 2);
  __bf16* ixa   = (__bf16*)alloc((size_t)TROWS * DM * 2);
  __bf16* ika   = (__bf16*)alloc((size_t)TROWS * DM * 2);
  __bf16* cxtg  = (__bf16*)alloc((size_t)2 * DM * 64 * 2);

  // fused weight-transpose + rmsnorm (3328 + 1024 + 8192 blocks)
  prep_kernel<<<dim3(12544), 256, 0, stream>>>(Win, WinT, Wout, WoutT, hidden, rmsw, hy);
  // GEMM1: M=8192, N=3328 -> 64*26 = 1664 blocks; groups 4m x 13n
  gemm2p<4, 13, 1><<<dim3((TROWS / 128) * (PD / 128)), 512, 0, stream>>>(
      hy, WinT, PD, DM, gbias, nullptr, nullptr, zbf, xbf, gbf, qbf, kbf);
  scan_kernel<<<512, 256, 0, stream>>>(gbf, xbf, kbf, ixa, ika, cxtg);
  attn_kernel<<<dim3(64, 16, 2), 256, 0, stream>>>(qbf, ixa, ika, cxtg, zbf, hy);
  // GEMM2: M=8192, N=1024 -> 64*8 = 512 blocks; groups 4m x 8n
  gemm2p<4, 8, 0><<<dim3((TROWS / 128) * (DM / 128)), 512, 0, stream>>>(
      hy, WoutT, DM, DM, nullptr, hidden, out, nullptr, nullptr, nullptr, nullptr, nullptr);
}

// Round 14
// 166.231 us; speedup vs baseline: 1.0364x; 1.0364x over previous
//
#include <hip/hip_runtime.h>
#include <hip/hip_bf16.h>

typedef __bf16 bf16x8 __attribute__((ext_vector_type(8)));
typedef __bf16 bf16x4 __attribute__((ext_vector_type(4)));
typedef float  f32x4  __attribute__((ext_vector_type(4)));

#define DM 1024
#define PD 3328
#define TROWS 8192   // bs*seq = 2*4096
#define SEQ 4096

__device__ __forceinline__ float sigmoidf(float x) { return 1.f / (1.f + __expf(-x)); }

__device__ __forceinline__ void gload16(const void* g, void* l) {
  __builtin_amdgcn_global_load_lds(
      (const __attribute__((address_space(1))) void*)g,
      (__attribute__((address_space(3))) void*)l, 16, 0, 0);
}

// ---------------- fused prep: tcvt(Win) + tcvt(Wout) + rmsnorm in ONE launch
__global__ __launch_bounds__(256) void prep_kernel(const float* __restrict__ Win,
                                                   __bf16* __restrict__ WinT,
                                                   const float* __restrict__ Wout,
                                                   __bf16* __restrict__ WoutT,
                                                   const float* __restrict__ hidden,
                                                   const float* __restrict__ rmsw,
                                                   __bf16* __restrict__ hbf) {
  const int id = blockIdx.x;
  const int tid = threadIdx.x;
  if (id < 4352) {
    __shared__ float tile[32][33];
    const float* in;  __bf16* out;  int K, N, bx, by;
    if (id < 3328) { in = Win;  out = WinT;  K = DM; N = PD; bx = id % 104; by = id / 104; }
    else           { in = Wout; out = WoutT; K = DM; N = DM; bx = (id - 3328) & 31; by = (id - 3328) >> 5; }
    int n0 = bx * 32, k0 = by * 32;
    int tx = tid & 31, ty = tid >> 5;   // 32 x 8
    for (int i = ty; i < 32; i += 8) tile[i][tx] = in[(size_t)(k0 + i) * N + n0 + tx];
    __syncthreads();
    for (int i = ty; i < 32; i += 8) out[(size_t)(n0 + i) * K + k0 + tx] = (__bf16)tile[tx][i];
  } else {
    int r = id - 4352;
    float4 v = ((const float4*)(hidden + (size_t)r * DM))[tid];
    float ss = v.x * v.x + v.y * v.y + v.z * v.z + v.w * v.w;
#pragma unroll
    for (int off = 32; off > 0; off >>= 1) ss += __shfl_xor(ss, off);
    __shared__ float wsum[4];
    int lane = tid & 63, wid = tid >> 6;
    if (lane == 0) wsum[wid] = ss;
    __syncthreads();
    float tot = wsum[0] + wsum[1] + wsum[2] + wsum[3];
    float inv = rsqrtf(tot * (1.f / 1024.f) + 1e-6f);
    float4 wl = ((const float4*)rmsw)[tid];
    bf16x4 o;
    o[0] = (__bf16)(v.x * inv * wl.x);
    o[1] = (__bf16)(v.y * inv * wl.y);
    o[2] = (__bf16)(v.z * inv * wl.z);
    o[3] = (__bf16)(v.w * inv * wl.w);
    *(bf16x4*)(hbf + (size_t)r * DM + tid * 4) = o;
  }
}

// ---------------- GEMM1: 256x128 tile, BK=32, dbuf LDS 48 KiB (2 blocks/CU),
// ONE barrier per K-step. R12-measured best-total config.
template <int GM, int GN, int EPI>
__global__ __launch_bounds__(512, 4) void gemm21(
    const __bf16* __restrict__ A, const __bf16* __restrict__ Bt,
    int N_out, int K,
    const float* __restrict__ gate_bias, const float* __restrict__ shortcut,
    float* __restrict__ outf, __bf16* __restrict__ zbf, __bf16* __restrict__ xbf,
    __bf16* __restrict__ gbf, __bf16* __restrict__ qbf, __bf16* __restrict__ kbf) {
  __shared__ __bf16 As[2][256 * 32];
  __shared__ __bf16 Bs[2][128 * 32];

  const int tid = threadIdx.x;
  const int lane = tid & 63, wid = tid >> 6;   // 8 waves
  const int wm = wid >> 1, wn = wid & 1;       // 4m x 2n, wave tile 64x64
  const int lr = lane & 15, hh = lane >> 4;

  // XCD swizzle + GM x GN grouped mapping (L2 working set ~4-5 MB/XCD)
  const int nwg = gridDim.x, cpx = nwg >> 3;
  const int swz = (blockIdx.x & 7) * cpx + (blockIdx.x >> 3);
  const int ntx = N_out >> 7;
  const int ngn = ntx / GN;
  const int g = swz / (GM * GN), l = swz % (GM * GN);
  const int gm = g / ngn, gn = g % ngn;
  const int m0 = (gm * GM + (l % GM)) << 8;
  const int n0 = (gn * GN + (l / GM)) << 7;

  f32x4 acc[4][4] = {};
  const int NT = K >> 5;

  const int arow0 = wm * 64 + lr;
  const int brow0 = wn * 64 + lr;

  auto stageA = [&](int kt, __bf16* lbuf) {
#pragma unroll
    for (int j = 0; j < 2; ++j) {
      int c = tid + j * 512;
      int row = c >> 2, s = c & 3;
      int lsw = s ^ ((row >> 1) & 3);   // inverse swizzle on the SOURCE
      gload16(&A[(size_t)(m0 + row) * K + kt + lsw * 8], lbuf + c * 8);
    }
  };
  auto stageB = [&](int kt, __bf16* lbuf) {
    int c = tid;
    int row = c >> 2, s = c & 3;
    int lsw = s ^ ((row >> 1) & 3);
    gload16(&Bt[(size_t)(n0 + row) * K + kt + lsw * 8], lbuf + c * 8);
  };
  auto fragrd = [&](const __bf16* buf, int row) -> bf16x8 {
    int s = hh ^ ((row >> 1) & 3);      // swizzled read
    return *(const bf16x8*)&buf[(row << 5) + (s << 3)];
  };

  // prologue: tile 0
  stageA(0, &As[0][0]);
  stageB(0, &Bs[0][0]);
  asm volatile("s_waitcnt vmcnt(0)" ::: "memory");
  __builtin_amdgcn_s_barrier();

  for (int t = 0; t < NT; ++t) {
    const __bf16* Ap = &As[t & 1][0];
    const __bf16* Bp = &Bs[t & 1][0];
    if (t + 1 < NT) {
      stageA((t + 1) << 5, &As[(t + 1) & 1][0]);
      stageB((t + 1) << 5, &Bs[(t + 1) & 1][0]);
    }
    {
      bf16x8 af[4], bf[4];
#pragma unroll
      for (int m = 0; m < 4; ++m) af[m] = fragrd(Ap, arow0 + m * 16);
#pragma unroll
      for (int n = 0; n < 4; ++n) bf[n] = fragrd(Bp, brow0 + n * 16);
      __builtin_amdgcn_s_setprio(1);
#pragma unroll
      for (int m = 0; m < 4; ++m)
#pragma unroll
        for (int n = 0; n < 4; ++n)
          acc[m][n] = __builtin_amdgcn_mfma_f32_16x16x32_bf16(af[m], bf[n], acc[m][n], 0, 0, 0);
      __builtin_amdgcn_s_setprio(0);
    }
    asm volatile("s_waitcnt vmcnt(0)" ::: "memory");
    __builtin_amdgcn_s_barrier();
  }

  // epilogue: C/D map col=lane&15, row=(lane>>4)*4+i
#pragma unroll
  for (int m = 0; m < 4; ++m) {
#pragma unroll
    for (int n = 0; n < 4; ++n) {
#pragma unroll
      for (int i = 0; i < 4; ++i) {
        int r = m0 + wm * 64 + m * 16 + (hh << 2) + i;
        int c = n0 + wn * 64 + n * 16 + lr;
        float v = acc[m][n][i];
        if (EPI == 1) {
          if (c < 1024)       zbf[(size_t)r * DM + c] = (__bf16)sigmoidf(v);
          else if (c < 2048)  xbf[(size_t)r * DM + (c - 1024)] = (__bf16)v;
          else if (c < 3072)  gbf[(size_t)r * DM + (c - 2048)] = (__bf16)sigmoidf(v + gate_bias[c - 2048]);
          else if (c < 3200)  qbf[(size_t)r * 128 + (c - 3072)] = (__bf16)v;
          else                kbf[(size_t)r * 128 + (c - 3200)] = (__bf16)v;
        } else {
          outf[(size_t)r * DM + c] = v + shortcut[(size_t)r * DM + c];
        }
      }
    }
  }
}

// ---------------- 2-phase MFMA GEMM 128x128/BK=64 (R10-verified) — GEMM2
template <int GN, int EPI>
__global__ __launch_bounds__(512, 4) void gemm2p(
    const __bf16* __restrict__ A, const __bf16* __restrict__ Bt,
    int N_out, int K,
    const float* __restrict__ gate_bias, const float* __restrict__ shortcut,
    float* __restrict__ outf, __bf16* __restrict__ zbf, __bf16* __restrict__ xbf,
    __bf16* __restrict__ gbf, __bf16* __restrict__ qbf, __bf16* __restrict__ kbf) {
  __shared__ __bf16 As[2][128 * 64];
  __shared__ __bf16 Bs[2][128 * 64];

  const int tid = threadIdx.x;
  const int lane = tid & 63, wid = tid >> 6;   // wid 0..7
  const int wr = wid >> 1, wc = wid & 1;       // 4 x 2 waves, wave tile 32(m) x 64(n)

  const int nwg = gridDim.x;
  const int cpx = nwg >> 3;
  const int swz = (blockIdx.x & 7) * cpx + (blockIdx.x >> 3);
  const int ntx = N_out >> 7;
  const int ngn = ntx / GN;
  const int g = swz / (8 * GN), l = swz % (8 * GN);
  const int gm = g / ngn, gn = g % ngn;
  const int m0 = (gm * 8 + (l & 7)) << 7;
  const int n0 = (gn * GN + (l >> 3)) << 7;

  f32x4 acc[2][4] = {};
  const int NT = K >> 6;

  const int arow0 = wr * 32 + (lane & 15);
  const int brow0 = wc * 64 + (lane & 15);

  auto stage = [&](const __bf16* src, int row0, int kt, __bf16* lbuf) {
#pragma unroll
    for (int j = 0; j < 2; ++j) {
      int off16 = tid + j * 512;        // 16B-chunk index; 8 chunks per row
      int row = off16 >> 3, slot = off16 & 7;
      int col = (slot ^ (row & 7)) << 3;  // inverse swizzle on the SOURCE
      gload16(&src[(size_t)(row0 + row) * K + kt + col], lbuf + off16 * 8);
    }
  };
  auto fragrd = [&](const __bf16* buf, int row, int ks) -> bf16x8 {
    int s = ((ks << 2) + (lane >> 4)) ^ (row & 7);   // swizzled read
    return *(const bf16x8*)&buf[(row << 6) + (s << 3)];
  };

  stage(A, m0, 0, &As[0][0]);
  stage(Bt, n0, 0, &Bs[0][0]);
  asm volatile("s_waitcnt vmcnt(0)" ::: "memory");
  __builtin_amdgcn_s_barrier();

  for (int t = 0; t < NT; ++t) {
    const __bf16* Ap = &As[t & 1][0];
    const __bf16* Bp = &Bs[t & 1][0];
    if (t + 1 < NT) {
      stage(A, m0, (t + 1) << 6, &As[(t + 1) & 1][0]);
      stage(Bt, n0, (t + 1) << 6, &Bs[(t + 1) & 1][0]);
    }
#pragma unroll
    for (int ks = 0; ks < 2; ++ks) {
      bf16x8 af[2], bf[4];
#pragma unroll
      for (int m = 0; m < 2; ++m) af[m] = fragrd(Ap, arow0 + m * 16, ks);
#pragma unroll
      for (int n = 0; n < 4; ++n) bf[n] = fragrd(Bp, brow0 + n * 16, ks);
      __builtin_amdgcn_s_setprio(1);
#pragma unroll
      for (int m = 0; m < 2; ++m)
#pragma unroll
        for (int n = 0; n < 4; ++n)
          acc[m][n] = __builtin_amdgcn_mfma_f32_16x16x32_bf16(af[m], bf[n], acc[m][n], 0, 0, 0);
      __builtin_amdgcn_s_setprio(0);
    }
    asm volatile("s_waitcnt vmcnt(0)" ::: "memory");
    __builtin_amdgcn_s_barrier();
  }

#pragma unroll
  for (int m = 0; m < 2; ++m) {
#pragma unroll
    for (int n = 0; n < 4; ++n) {
#pragma unroll
      for (int i = 0; i < 4; ++i) {
        int r = m0 + wr * 32 + m * 16 + ((lane >> 4) << 2) + i;
        int c = n0 + wc * 64 + n * 16 + (lane & 15);
        float v = acc[m][n][i];
        if (EPI == 1) {
          if (c < 1024)       zbf[(size_t)r * DM + c] = (__bf16)sigmoidf(v);
          else if (c < 2048)  xbf[(size_t)r * DM + (c - 1024)] = (__bf16)v;
          else if (c < 3072)  gbf[(size_t)r * DM + (c - 2048)] = (__bf16)sigmoidf(v + gate_bias[c - 2048]);
          else if (c < 3200)  qbf[(size_t)r * 128 + (c - 3072)] = (__bf16)v;
          else                kbf[(size_t)r * 128 + (c - 3200)] = (__bf16)v;
        } else {
          outf[(size_t)r * DM + c] = v + shortcut[(size_t)r * DM + c];
        }
      }
    }
  }
}

// ---------------- per-chunk first-order scan; also emits chunk_x TRANSPOSED
__global__ __launch_bounds__(256) void scan_kernel(const __bf16* __restrict__ g,
                                                   const __bf16* __restrict__ x,
                                                   const __bf16* __restrict__ kin,
                                                   __bf16* __restrict__ ixa,
                                                   __bf16* __restrict__ ika,
                                                   __bf16* __restrict__ cxtg) {
  int bx = blockIdx.x;            // 2*64*4 = 512 blocks
  int part = bx & 3;
  int c = (bx >> 2) & 63;
  int b = bx >> 8;
  int d = part * 256 + threadIdx.x;
  size_t base = (size_t)b * SEQ + (size_t)c * 64;
  float sx = 0.f, sk = 0.f;
  for (int t = 0; t < 64; ++t) {
    size_t row = base + t;
    float gg = (float)g[row * DM + d];
    float xv = (float)x[row * DM + d];
    float kv = (float)kin[row * 128 + (d & 127)];
    sx = gg * (sx - xv) + xv;   // = g*prev + (1-g)*x
    sk = gg * (sk - kv) + kv;
    ixa[row * DM + d] = (__bf16)sx;
    ika[row * DM + d] = (__bf16)sk;
    if (t == 0) cxtg[((size_t)b * DM + d) * 64 + c] = (__bf16)sx;
  }
}

// ---------------- attention v2 (R10-measured): block = (qtile, head, batch)
__global__ __launch_bounds__(256) void attn_kernel(const __bf16* __restrict__ qbf,
                                                   const __bf16* __restrict__ ixa,
                                                   const __bf16* __restrict__ ika,
                                                   const __bf16* __restrict__ cxtg,
                                                   const __bf16* __restrict__ zbf,
                                                   __bf16* __restrict__ y) {
  const int qt = blockIdx.x;   // 0..63 query chunk
  const int h  = blockIdx.y;   // 0..15
  const int b  = blockIdx.z;   // 0..1
  const int tid = threadIdx.x;
  const int lane = tid & 63, wd = tid >> 6;

  __shared__ __bf16 qs[64 * 72];    // q rows [s][d]
  __shared__ __bf16 ck[64 * 72];    // chunk_k rows [c][d]
  __shared__ __bf16 cxT[64 * 72];   // chunk_x transposed [j][c]
  __shared__ __bf16 pb[64 * 72];    // softmax weights [s][c]
  __shared__ float sc[64 * 65];     // scores [s][c]
  __shared__ float rden[64], iwd[64], rlse[64];

  const size_t base = (size_t)b * SEQ;

  for (int i = tid; i < 512; i += 256) {
    int row = i >> 3, part = i & 7;
    *(bf16x8*)&qs[row * 72 + part * 8] =
        *(const bf16x8*)&qbf[(base + qt * 64 + row) * 128 + (h & 1) * 64 + part * 8];
    *(bf16x8*)&ck[row * 72 + part * 8] =
        *(const bf16x8*)&ika[(base + (size_t)row * 64) * DM + h * 64 + part * 8];
    *(bf16x8*)&cxT[row * 72 + part * 8] =
        *(const bf16x8*)&cxtg[((size_t)b * DM + h * 64 + row) * 64 + part * 8];
  }
  __syncthreads();

  // scores = scale * Q . chunk_k^T  -> sc[s][c]
  {
    f32x4 d4[4] = {};
#pragma unroll
    for (int kk = 0; kk < 64; kk += 32) {
      bf16x8 a = *(const bf16x8*)&qs[(wd * 16 + (lane & 15)) * 72 + kk + (lane >> 4) * 8];
#pragma unroll
      for (int ni = 0; ni < 4; ++ni) {
        bf16x8 bb = *(const bf16x8*)&ck[(ni * 16 + (lane & 15)) * 72 + kk + (lane >> 4) * 8];
        d4[ni] = __builtin_amdgcn_mfma_f32_16x16x32_bf16(a, bb, d4[ni], 0, 0, 0);
      }
    }
#pragma unroll
    for (int ni = 0; ni < 4; ++ni)
#pragma unroll
      for (int i = 0; i < 4; ++i) {
        int qrow = wd * 16 + (lane >> 4) * 4 + i;
        int c = ni * 16 + (lane & 15);
        sc[qrow * 65 + c] = 0.125f * d4[ni][i];
      }
  }

  // intra_lse, 4 lanes per q-row
  {
    int s = tid >> 2, p = tid & 3;
    const __bf16* krow = &ika[(base + qt * 64 + s) * DM + h * 64 + p * 16];
    float dot = 0.f;
#pragma unroll
    for (int half = 0; half < 2; ++half) {
      bf16x8 qa = *(const bf16x8*)&qs[s * 72 + p * 16 + half * 8];
      bf16x8 ka = *(const bf16x8*)&krow[half * 8];
#pragma unroll
      for (int e = 0; e < 8; ++e) dot += (float)qa[e] * (float)ka[e];
    }
    dot += __shfl_xor(dot, 1);
    dot += __shfl_xor(dot, 2);
    if (p == 0) rlse[s] = 0.125f * dot;
  }
  __syncthreads();

  // softmax, 4 lanes per q-row
  {
    int s = tid >> 2, p = tid & 3;
    float lse = rlse[s];
    float m = -1e30f;
#pragma unroll
    for (int k = 0; k < 16; ++k) {
      int c = p * 16 + k;
      if (c < qt) m = fmaxf(m, sc[s * 65 + c]);
    }
    m = fmaxf(m, __shfl_xor(m, 1));
    m = fmaxf(m, __shfl_xor(m, 2));
    m = fmaxf(m, lse);
    float den = 0.f;
    bf16x8 w0, w1;
#pragma unroll
    for (int k = 0; k < 16; ++k) {
      int c = p * 16 + k;
      float wv = (c < qt) ? __expf(sc[s * 65 + c] - m) : 0.f;
      if (k < 8) w0[k] = (__bf16)wv; else w1[k - 8] = (__bf16)wv;
      den += wv;
    }
    *(bf16x8*)&pb[s * 72 + p * 16] = w0;
    *(bf16x8*)&pb[s * 72 + p * 16 + 8] = w1;
    den += __shfl_xor(den, 1);
    den += __shfl_xor(den, 2);
    float iw = __expf(lse - m);
    if (p == 0) {
      rden[s] = 1.f / (den + iw);
      iwd[s] = iw;
    }
  }
  __syncthreads();

  // PV: out[s][j] = sum_c pb[s][c] * cxT[j][c]
  {
    f32x4 d4[4] = {};
#pragma unroll
    for (int kk = 0; kk < 64; kk += 32) {
      bf16x8 a = *(const bf16x8*)&pb[(wd * 16 + (lane & 15)) * 72 + kk + (lane >> 4) * 8];
#pragma unroll
      for (int ni = 0; ni < 4; ++ni) {
        bf16x8 bb = *(const bf16x8*)&cxT[(ni * 16 + (lane & 15)) * 72 + kk + (lane >> 4) * 8];
        d4[ni] = __builtin_amdgcn_mfma_f32_16x16x32_bf16(a, bb, d4[ni], 0, 0, 0);
      }
    }
#pragma unroll
    for (int ni = 0; ni < 4; ++ni)
#pragma unroll
      for (int i = 0; i < 4; ++i) {
        int qrow = wd * 16 + (lane >> 4) * 4 + i;
        int j = ni * 16 + (lane & 15);
        size_t srow = base + qt * 64 + qrow;
        float ix = (float)ixa[srow * DM + h * 64 + j];
        float outv = (d4[ni][i] + iwd[qrow] * ix) * rden[qrow];
        float zv = (float)zbf[srow * DM + h * 64 + j];
        y[srow * DM + h * 64 + j] = (__bf16)(outv * zv);
      }
  }
}

// ---------------- launcher
extern "C" void kernel_launch(void* const* d_in, const int* in_sizes, int n_in,
                              void* d_out, int out_size, void* d_ws, size_t ws_size,
                              hipStream_t stream) {
  const float* hidden = (const float*)d_in[0];
  const float* rmsw   = (const float*)d_in[1];
  const float* Win    = (const float*)d_in[2];
  const float* gbias  = (const float*)d_in[3];
  const float* Wout   = (const float*)d_in[4];
  float* out = (float*)d_out;

  char* ws = (char*)d_ws;
  size_t o = 0;
  auto alloc = [&](size_t bytes) { char* p = ws + o; o += (bytes + 255) & ~(size_t)255; return p; };
  __bf16* WinT  = (__bf16*)alloc((size_t)PD * DM * 2);
  __bf16* WoutT = (__bf16*)alloc((size_t)DM * DM * 2);
  __bf16* hy    = (__bf16*)alloc((size_t)TROWS * DM * 2);  // h_bf, reused as y after GEMM1
  __bf16* zbf   = (__bf16*)alloc((size_t)TROWS * DM * 2);
  __bf16* xbf   = (__bf16*)alloc((size_t)TROWS * DM * 2);
  __bf16* gbf   = (__bf16*)alloc((size_t)TROWS * DM * 2);
  __bf16* qbf   = (__bf16*)alloc((size_t)TROWS * 128 * 2);
  __bf16* kbf   = (__bf16*)alloc((size_t)TROWS * 128 * 2);
  __bf16* ixa   = (__bf16*)alloc((size_t)TROWS * DM * 2);
  __bf16* ika   = (__bf16*)alloc((size_t)TROWS * DM * 2);
  __bf16* cxtg  = (__bf16*)alloc((size_t)2 * DM * 64 * 2);

  // fused weight-transpose + rmsnorm (3328 + 1024 + 8192 blocks)
  prep_kernel<<<dim3(12544), 256, 0, stream>>>(Win, WinT, Wout, WoutT, hidden, rmsw, hy);
  // GEMM1: 256x128 tiles -> (8192/256)*(3328/128) = 32*26 = 832 blocks (%8==0)
  gemm21<4, 13, 1><<<dim3(832), 512, 0, stream>>>(
      hy, WinT, PD, DM, gbias, nullptr, nullptr, zbf, xbf, gbf, qbf, kbf);
  scan_kernel<<<512, 256, 0, stream>>>(gbf, xbf, kbf, ixa, ika, cxtg);
  attn_kernel<<<dim3(64, 16, 2), 256, 0, stream>>>(qbf, ixa, ika, cxtg, zbf, hy);
  // GEMM2: M=8192, N=1024 -> 64*8 = 512 blocks; groups 8m x 8n (R10/R12 config)
  gemm2p<8, 0><<<dim3((TROWS / 128) * (DM / 128)), 512, 0, stream>>>(
      hy, WoutT, DM, DM, nullptr, hidden, out, nullptr, nullptr, nullptr, nullptr, nullptr);
}